// Round 5
// baseline (3212.981 us; speedup 1.0000x reference)
//
#include <hip/hip_runtime.h>
#include <stdint.h>

// Round 4: fps — keep state in registers (anti-remat asm pins), packed-f32 pairs,
// centroid broadcast through registers/LDS instead of global loads, single barrier
// (double-buffered partials). group — waves 1-3 write the anchor half during
// wave-0's ball query. All comparison arithmetic bit-identical to Round 2/3.

#define NBATCH 8
#define NPTS   8192
#define NCH    128
#define NGROUP 2048
#define NK     24
#define ROWLEN (2 * NCH + 3)   // 259

typedef float v2f __attribute__((ext_vector_type(2)));

__device__ __forceinline__ float sq3_nofma(float dx, float dy, float dz) {
#pragma clang fp contract(off)
  return dx * dx + dy * dy + dz * dz;
}

// numpy einsum contracted inner loop: acc = a0*b0; acc = fma(a1,b1,acc); acc = fma(a2,b2,acc)
__device__ __forceinline__ float dot3_fma(float ax, float ay, float az,
                                          float bx, float by, float bz) {
  float acc = __fmul_rn(ax, bx);
  acc = __fmaf_rn(ay, by, acc);
  acc = __fmaf_rn(az, bz, acc);
  return acc;
}

__device__ __forceinline__ float ballquery_sqr(float srcSq, float dstSq, float dot) {
#pragma clang fp contract(off)
  return (srcSq + dstSq) - 2.0f * dot;
}

template <int CTRL>
__device__ __forceinline__ float maxdpp(float v) {
  int s = __builtin_amdgcn_update_dpp(__builtin_bit_cast(int, v),
                                      __builtin_bit_cast(int, v),
                                      CTRL, 0xF, 0xF, false);
  return fmaxf(v, __builtin_bit_cast(float, s));
}

__device__ __forceinline__ float readlane_f(float v, int lane) {
  return __builtin_bit_cast(float,
      __builtin_amdgcn_readlane(__builtin_bit_cast(int, v), lane));
}

__global__ __launch_bounds__(1024) void fps_kernel(const float* __restrict__ xyz,
                                                   int* __restrict__ fps_idx) {
  const int b = blockIdx.x;
  const int t = threadIdx.x;
  const int lane = t & 63;
  const int w = t >> 6;
  const float* xb = xyz + (size_t)b * NPTS * 3;
  const int base = t << 3;   // contiguous ownership [8t, 8t+8)

  // 96B contiguous per thread, 16B aligned -> 6x float4
  const float4* q = (const float4*)(xb + (size_t)base * 3);
  const float4 A = q[0], Bq = q[1], C = q[2], D = q[3], E = q[4], F = q[5];
  float xx[8] = {A.x, A.w, Bq.z, C.y, D.x, D.w, E.z, F.y};
  float yy[8] = {A.y, Bq.x, Bq.w, C.z, D.y, E.x, E.w, F.z};
  float zz[8] = {A.z, Bq.y, C.x, C.w, D.z, E.y, F.x, F.w};
#pragma unroll
  for (int i = 0; i < 8; ++i)
    asm volatile("" : "+v"(xx[i]), "+v"(yy[i]), "+v"(zz[i]));  // pin in VGPRs (no remat/reload)

  v2f px2[4], py2[4], pz2[4], d2[4];
#pragma unroll
  for (int p = 0; p < 4; ++p) {
    px2[p] = (v2f){xx[2 * p], xx[2 * p + 1]};
    py2[p] = (v2f){yy[2 * p], yy[2 * p + 1]};
    pz2[p] = (v2f){zz[2 * p], zz[2 * p + 1]};
    d2[p] = (v2f){1e10f, 1e10f};
  }

  __shared__ float s_v[2][16], s_x[2][16], s_y[2][16], s_z[2][16];
  __shared__ int s_i[2][16];

  float cx = xb[0], cy = xb[1], cz = xb[2];   // centroid 0 = point 0
  if (t == 0) fps_idx[b * NGROUP + 0] = 0;

  for (int s = 1; s < NGROUP; ++s) {
    // ---- phase 1: min-update + local argmax (packed, contraction-free) ----
    const v2f c2x = (v2f){cx, cx}, c2y = (v2f){cy, cy}, c2z = (v2f){cz, cz};
    float lv = -1.0f;
    int li = base;
#pragma unroll
    for (int p = 0; p < 4; ++p) {
      v2f dd;
      {
#pragma clang fp contract(off)
        const v2f dx = px2[p] - c2x;
        const v2f dy = py2[p] - c2y;
        const v2f dz = pz2[p] - c2z;
        dd = dx * dx + dy * dy + dz * dz;   // ((x+y)+z) per half, never fused
      }
      const float n0 = fminf(d2[p].x, dd.x);
      const float n1 = fminf(d2[p].y, dd.y);
      d2[p].x = n0;
      d2[p].y = n1;
      if (n0 > lv) { lv = n0; li = base + 2 * p; }       // strict > : first index wins
      if (n1 > lv) { lv = n1; li = base + 2 * p + 1; }
    }

    // ---- wave argmax via DPP + ballot (first index on ties) ----
    float v = lv;
    v = maxdpp<0x111>(v); v = maxdpp<0x112>(v); v = maxdpp<0x114>(v); v = maxdpp<0x118>(v);
    v = maxdpp<0x142>(v); v = maxdpp<0x143>(v);
    const float wmax = readlane_f(v, 63);
    const unsigned long long m = __ballot(lv == wmax);
    const int wl = (int)__builtin_ctzll(m);              // lowest lane = lowest index
    const int wli = __builtin_amdgcn_readlane(li, wl);

    // winner coords from the winner lane's registers (uniform local idx select)
    const int iw = wli & 7;
    v2f sa, sb, sv;
    sa = (iw & 2) ? px2[1] : px2[0];  sb = (iw & 2) ? px2[3] : px2[2];
    sv = (iw & 4) ? sb : sa;
    const float selx = (iw & 1) ? sv.y : sv.x;
    sa = (iw & 2) ? py2[1] : py2[0];  sb = (iw & 2) ? py2[3] : py2[2];
    sv = (iw & 4) ? sb : sa;
    const float sely = (iw & 1) ? sv.y : sv.x;
    sa = (iw & 2) ? pz2[1] : pz2[0];  sb = (iw & 2) ? pz2[3] : pz2[2];
    sv = (iw & 4) ? sb : sa;
    const float selz = (iw & 1) ? sv.y : sv.x;
    const float wx = readlane_f(selx, wl);
    const float wy = readlane_f(sely, wl);
    const float wz = readlane_f(selz, wl);

    const int buf = s & 1;
    if (lane == 0) {
      s_v[buf][w] = wmax; s_i[buf][w] = wli;
      s_x[buf][w] = wx;   s_y[buf][w] = wy;  s_z[buf][w] = wz;
    }
    __syncthreads();   // single barrier per iteration (double-buffered partials)

    // ---- phase 2: every wave reduces the 16 partials ----
    const int l16 = lane & 15;
    const float pv = s_v[buf][l16];
    const int   pi = s_i[buf][l16];
    const float qx = s_x[buf][l16];
    const float qy = s_y[buf][l16];
    const float qz = s_z[buf][l16];
    float r = pv;
    r = maxdpp<0x111>(r); r = maxdpp<0x112>(r); r = maxdpp<0x114>(r); r = maxdpp<0x118>(r);
    const float bmax = readlane_f(r, 15);
    const unsigned long long m2 = __ballot(pv == bmax);
    const int wwin = (int)__builtin_ctzll(m2);           // lowest wave = lowest index
    const int bi = __builtin_amdgcn_readlane(pi, wwin);
    cx = readlane_f(qx, wwin);
    cy = readlane_f(qy, wwin);
    cz = readlane_f(qz, wwin);
    if (t == 0) fps_idx[b * NGROUP + s] = bi;
  }
}

__global__ __launch_bounds__(256) void group_kernel(const float* __restrict__ xyz,
                                                    const float* __restrict__ points,
                                                    const int* __restrict__ fps_idx,
                                                    float* __restrict__ out) {
  const int gb = blockIdx.x;        // b*NGROUP + g
  const int b = gb >> 11;
  const int tid = threadIdx.x;
  const float* xb = xyz + (size_t)b * NPTS * 3;
  const float* pb = points + (size_t)b * NPTS * NCH;

  __shared__ int s_idx[NK];

  const int a_idx = fps_idx[gb];
  const float cx = xb[a_idx * 3 + 0];
  const float cy = xb[a_idx * 3 + 1];
  const float cz = xb[a_idx * 3 + 2];
  const float srcSq = sq3_nofma(cx, cy, cz);
  const float R2 = (float)(0.2 * 0.2);

  float* op = out + (size_t)NBATCH * NGROUP * 3 + (size_t)gb * (NK * ROWLEN);
  const float* anchor = pb + (size_t)a_idx * NCH;

  if (tid < 64) {
    // ---- wave 0: ball query (bit-identical to Round 3) ----
    int cnt = 0;
    int first = 0;
    const unsigned long long below = ((unsigned long long)1 << tid) - 1ull;
    for (int chunk = 0; chunk < NPTS / 128; ++chunk) {
      const int n0 = (chunk << 7) + (tid << 1);        // 2 points per lane
      const float* p = xb + (size_t)n0 * 3;            // 24B-aligned
      const float2 A = *(const float2*)(p + 0);        // x0 y0
      const float2 Bv = *(const float2*)(p + 2);       // z0 x1
      const float2 C = *(const float2*)(p + 4);        // y1 z1
      const float x0 = A.x, y0 = A.y, z0 = Bv.x;
      const float x1 = Bv.y, y1 = C.x, z1 = C.y;

      const float sqr0 = ballquery_sqr(srcSq, sq3_nofma(x0, y0, z0),
                                       dot3_fma(cx, cy, cz, x0, y0, z0));
      const float sqr1 = ballquery_sqr(srcSq, sq3_nofma(x1, y1, z1),
                                       dot3_fma(cx, cy, cz, x1, y1, z1));
      const bool ok0 = !(sqr0 > R2);
      const bool ok1 = !(sqr1 > R2);
      const unsigned long long m0 = __ballot(ok0);
      const unsigned long long m1 = __ballot(ok1);
      if (cnt == 0 && (m0 | m1)) {
        const int f0 = m0 ? (int)__builtin_ctzll(m0) : 64;
        const int f1 = m1 ? (int)__builtin_ctzll(m1) : 64;
        first = (f0 <= f1) ? ((chunk << 7) + 2 * f0) : ((chunk << 7) + 2 * f1 + 1);
      }
      const int p0 = cnt + (int)__popcll(m0 & below) + (int)__popcll(m1 & below);
      const int p1 = p0 + (ok0 ? 1 : 0);
      if (ok0 && p0 < NK) s_idx[p0] = n0;
      if (ok1 && p1 < NK) s_idx[p1] = n0 + 1;
      cnt += (int)__popcll(m0) + (int)__popcll(m1);
      if (cnt >= NK) break;
    }
    if (tid >= cnt && tid < NK) s_idx[tid] = first;  // pad with first in-radius index
  } else {
    // ---- waves 1-3: idx-independent half (anchor columns 131..258 + new_xyz) ----
    if (tid == 64) {
      float* onx = out + (size_t)gb * 3;
      onx[0] = cx; onx[1] = cy; onx[2] = cz;
    }
    for (int j = tid - 64; j < NK * NCH; j += 192) {
      const int k = j >> 7;            // row
      const int c = j & 127;           // anchor channel
      op[k * ROWLEN + (NCH + 3) + c] = anchor[c];
    }
  }
  __syncthreads();

  // ---- all threads: idx-dependent columns 0..130 ----
  for (int j = tid; j < NK * (NCH + 3); j += 256) {
    const int k = j / (NCH + 3);
    const int c = j - k * (NCH + 3);
    const int si = s_idx[k];
    op[k * ROWLEN + c] = (c < NCH) ? pb[(size_t)si * NCH + c] : xb[si * 3 + (c - NCH)];
  }
}

extern "C" void kernel_launch(void* const* d_in, const int* in_sizes, int n_in,
                              void* d_out, int out_size, void* d_ws, size_t ws_size,
                              hipStream_t stream) {
  const float* xyz = (const float*)d_in[0];
  const float* points = (const float*)d_in[1];
  float* out = (float*)d_out;
  int* fps_idx = (int*)d_ws;  // 8*2048 ints

  fps_kernel<<<dim3(NBATCH), dim3(1024), 0, stream>>>(xyz, fps_idx);
  group_kernel<<<dim3(NBATCH * NGROUP), dim3(256), 0, stream>>>(xyz, points, fps_idx, out);
}